// Round 4
// baseline (106.641 us; speedup 1.0000x reference)
//
#include <hip/hip_runtime.h>

// NodeEdgeProjection: out[b, e, f] = x[b, e/127, f]
// B=128, N=128, n_edges = 128*127 = 16256, F=64, fp32.
//
// Round-3 structure: one block per (b, 8-node group); grid = 128*16 = 2048
// = exactly 8 blocks/CU, one-shot. Each thread caches 8 row-fragments
// (f32x4) in registers -- the block's startup load latency (~900 cy, zero
// cross-block reuse in x) is paid ONCE per CU slot instead of 8x as in the
// previous 16384-tiny-block version. Store loop: 64 fully-coalesced 16 B
// stores/thread into a contiguous 254 KB span. Plain stores (no nt), matching
// the 6.9 TB/s fill-kernel configuration.

typedef float f32x4 __attribute__((ext_vector_type(4)));

constexpr unsigned Bn = 128;
constexpr unsigned Nn = 128;
constexpr unsigned Fn = 64;
constexpr unsigned NE = Nn * (Nn - 1);   // 16256
constexpr unsigned F4 = Fn / 4;          // 16 float4 per feature row
constexpr unsigned NG = 8;               // nodes per block
constexpr unsigned GROUPS = Nn / NG;     // 16 groups per batch

__global__ __launch_bounds__(256) void node_edge_bcast8(
    const f32x4* __restrict__ x, f32x4* __restrict__ out) {
    const unsigned blk  = blockIdx.x;        // = b*GROUPS + g
    const unsigned b    = blk >> 4;          // / GROUPS
    const unsigned g    = blk & (GROUPS - 1);
    const unsigned tid  = threadIdx.x;
    const unsigned f4   = tid & (F4 - 1);    // feature quad 0..15
    const unsigned half = tid >> 4;          // starting replica row 0..15

    const unsigned node0 = g * NG;

    // 8 pipelined loads per thread; 4 lanes/wave share each address.
    const f32x4* src = x + (b * Nn + node0) * F4 + f4;
    f32x4 v[NG];
    #pragma unroll
    for (unsigned n = 0; n < NG; ++n) v[n] = src[n * F4];

    // 8 nodes x 127 replica rows each; a wave covers 4 consecutive rows x
    // 16 quads = 4 KB contiguous per store instruction.
    f32x4* dst = out + (b * NE + node0 * (Nn - 1)) * F4 + f4;
    #pragma unroll
    for (unsigned n = 0; n < NG; ++n) {
        f32x4* dn = dst + n * (Nn - 1) * F4;
        #pragma unroll
        for (unsigned r = half; r < Nn - 1; r += 16) {
            dn[r * F4] = v[n];
        }
    }
}

extern "C" void kernel_launch(void* const* d_in, const int* in_sizes, int n_in,
                              void* d_out, int out_size, void* d_ws, size_t ws_size,
                              hipStream_t stream) {
    const f32x4* x = (const f32x4*)d_in[0];
    f32x4* out = (f32x4*)d_out;

    node_edge_bcast8<<<Bn * GROUPS, 256, 0, stream>>>(x, out);
}